// Round 3
// baseline (694.965 us; speedup 1.0000x reference)
//
#include <hip/hip_runtime.h>

// EdgeConv fused GNN: msg-MLP (E×[160→128→128→64]+LN) → segment_sum → upd-MLP (N×[128→128→128→64]+LN)+res
// R3: kill the fp32 atomic scatter (R2 counters: 631MB WRITE = L2 RMW thrash from 25.6M atomics).
// Aggregation by gather instead: CSR build (int-atomic hist + 1-block scan + scatter), then
// agg_kernel sums msg rows per node (coalesced reads, zero fp atomics).
// bf16 MFMA 16x16x32, fp32 accum; weights pre-transposed bf16 [n][k] in d_ws.

typedef __attribute__((ext_vector_type(8))) short s16x8;   // 8 bf16 (4 VGPRs) — MFMA A/B frag
typedef __attribute__((ext_vector_type(4))) float f32x4;   // MFMA C/D frag
typedef __attribute__((ext_vector_type(4))) unsigned short u16x4;

__device__ __forceinline__ unsigned short f2bf(float x) {
  union { float f; unsigned u; } v; v.f = x;
  unsigned r = v.u + 0x7fffu + ((v.u >> 16) & 1u);   // RNE
  return (unsigned short)(r >> 16);
}

// ---------------- weight transpose+convert: wts[off + n*K + k] = bf16(src[k*N + n]) ----------------
// layout (ushort elems): mW1t @0 (128x160), mW2t @20480 (128x128), mW3t @36864 (64x128),
//                        uW1t @45056 (128x128), uW2t @61440 (128x128), uW3t @77824 (64x128); total 86016
__global__ __launch_bounds__(256) void wconv(
    const float* __restrict__ mW1, const float* __restrict__ mW2, const float* __restrict__ mW3,
    const float* __restrict__ uW1, const float* __restrict__ uW2, const float* __restrict__ uW3,
    unsigned short* __restrict__ wts) {
  int t = blockIdx.x * 256 + threadIdx.x;
  const float* src; int K, N, off;
  if      (t < 20480) { src = mW1; K = 160; N = 128; off = 0;     }
  else if (t < 36864) { src = mW2; K = 128; N = 128; off = 20480; }
  else if (t < 45056) { src = mW3; K = 128; N = 64;  off = 36864; }
  else if (t < 61440) { src = uW1; K = 128; N = 128; off = 45056; }
  else if (t < 77824) { src = uW2; K = 128; N = 128; off = 61440; }
  else if (t < 86016) { src = uW3; K = 128; N = 64;  off = 77824; }
  else return;
  int local = t - off;
  int n = local / K, k = local - n * K;
  wts[off + n * K + k] = f2bf(src[k * N + n]);
}

// ---------------- CSR build ----------------
__global__ __launch_bounds__(256) void hist_kernel(const int* __restrict__ dstI,
                                                   int* __restrict__ deg, int E) {
  int t = blockIdx.x * 256 + threadIdx.x;
  if (t < E) atomicAdd(&deg[dstI[t]], 1);
}

__global__ __launch_bounds__(1024) void scan_kernel(const int* __restrict__ deg,
                                                    int* __restrict__ rowptr,
                                                    int* __restrict__ cursor, int Nn) {
  __shared__ int part[1024], offs[1024];
  int t = threadIdx.x;
  int C = (Nn + 1023) / 1024;
  int lo = t * C, hi = lo + C < Nn ? lo + C : Nn;
  int sum = 0;
  for (int i = lo; i < hi; i++) sum += deg[i];
  part[t] = sum;
  __syncthreads();
  if (t == 0) {
    int run = 0;
    for (int i = 0; i < 1024; i++) { offs[i] = run; run += part[i]; }
  }
  __syncthreads();
  int run = offs[t];
  for (int i = lo; i < hi; i++) { rowptr[i] = run; cursor[i] = run; run += deg[i]; }
  if (t == 1023) rowptr[Nn] = offs[1023] + part[1023];
}

__global__ __launch_bounds__(256) void scatter_kernel(const int* __restrict__ dstI,
                                                      int* __restrict__ cursor,
                                                      int* __restrict__ csr, int E) {
  int t = blockIdx.x * 256 + threadIdx.x;
  if (t < E) {
    int pos = atomicAdd(&cursor[dstI[t]], 1);
    csr[pos] = t;
  }
}

// ---------------- MFMA layer: wave w computes rows [16w,16w+16) x (16*NT cols) ----------------
// A in LDS (row-major, stride ASTR ushorts); B read from GLOBAL wts (n-major, stride K) — L1/L2 hit.
template<int KSTEPS, int NT, int ASTR, int K>
__device__ __forceinline__ void do_layer(const unsigned short* A,
                                         const unsigned short* __restrict__ Bg,
                                         f32x4 (&acc)[8], int w, int quad, int l15) {
  f32x4 z = {0.f, 0.f, 0.f, 0.f};
  #pragma unroll
  for (int j = 0; j < NT; j++) acc[j] = z;
  #pragma unroll
  for (int kb = 0; kb < KSTEPS; kb++) {
    s16x8 a = *(const s16x8*)&A[(w * 16 + l15) * ASTR + kb * 32 + quad * 8];
    #pragma unroll
    for (int nt = 0; nt < NT; nt++) {
      s16x8 b = *(const s16x8*)&Bg[(nt * 16 + l15) * K + kb * 32 + quad * 8];
      acc[nt] = __builtin_amdgcn_mfma_f32_16x16x32_bf16(a, b, acc[nt], 0, 0, 0);
    }
  }
}

// bias + ReLU + cvt bf16 + store to LDS (next layer's A tile). C/D map: row=quad*4+r, col=nt*16+l15.
template<int NT, int DSTR>
__device__ __forceinline__ void store_relu_bf16(f32x4 (&acc)[8], const float* __restrict__ bias,
                                                unsigned short* dst, int w, int quad, int l15) {
  #pragma unroll
  for (int nt = 0; nt < NT; nt++) {
    float b = bias[nt * 16 + l15];
    int rowbase = w * 16 + quad * 4;
    #pragma unroll
    for (int r = 0; r < 4; r++) {
      float v = acc[nt][r] + b;
      v = v > 0.f ? v : 0.f;
      dst[(rowbase + r) * DSTR + nt * 16 + l15] = f2bf(v);
    }
  }
}

// bias (no relu) fp32 store to LN buffer (stride 65 floats, conflict-padded)
__device__ __forceinline__ void store_preln(f32x4 (&acc)[8], const float* __restrict__ bias,
                                            float* lnbuf, int w, int quad, int l15) {
  #pragma unroll
  for (int nt = 0; nt < 4; nt++) {
    float b = bias[nt * 16 + l15];
    #pragma unroll
    for (int r = 0; r < 4; r++)
      lnbuf[(w * 16 + quad * 4 + r) * 65 + nt * 16 + l15] = acc[nt][r] + b;
  }
}

// ---------------- message MLP kernel: 64 edges / block, 256 threads (4 waves), NO atomics ----------------
__global__ __launch_bounds__(256, 4) void msg_kernel(
    const float* __restrict__ h, const int* __restrict__ ei, const float* __restrict__ ea,
    const unsigned short* __restrict__ wts,
    const float* __restrict__ mb1, const float* __restrict__ mb2, const float* __restrict__ mb3,
    const float* __restrict__ mg, const float* __restrict__ mbt,
    float* __restrict__ msg_out, int E) {
  // buf0 21504B: X(64x168 bf16) -> act2(64x136)
  // buf1 17408B: act1(64x136)   -> lnbuf(64x65 f32 = 16640)
  __shared__ __align__(16) unsigned char smem[21504 + 17408 + 512];
  unsigned short* buf0 = (unsigned short*)smem;
  unsigned short* buf1 = (unsigned short*)(smem + 21504);
  float* stats = (float*)(smem + 21504 + 17408);
  float* lnbuf = (float*)buf1;

  const int tid = threadIdx.x;
  const int w = tid >> 6, lane = tid & 63, quad = lane >> 4, l15 = lane & 15;
  const int e0 = blockIdx.x * 64;
  const int* srcI = ei;
  const int* dstI = ei + E;

  // ---- stage X = [h[src] | h[dst] | edge_attr] -> buf0 bf16, stride 168
  for (int idx = tid; idx < 64 * 40; idx += 256) {
    int er = idx / 40, seg = idx - er * 40;    // 40 float4 chunks per edge
    int e = e0 + er;
    u16x4 o = {0, 0, 0, 0};
    if (e < E) {
      const float* p;
      if (seg < 16)      p = h + (size_t)srcI[e] * 64 + seg * 4;
      else if (seg < 32) p = h + (size_t)dstI[e] * 64 + (seg - 16) * 4;
      else               p = ea + (size_t)e * 32 + (seg - 32) * 4;
      float4 v = *(const float4*)p;
      o[0] = f2bf(v.x); o[1] = f2bf(v.y); o[2] = f2bf(v.z); o[3] = f2bf(v.w);
    }
    *(u16x4*)&buf0[er * 168 + seg * 4] = o;
  }
  __syncthreads();

  f32x4 acc[8];
  // L1: 160 -> 128 (B from global, L1/L2-resident)
  do_layer<5, 8, 168, 160>(buf0, wts, acc, w, quad, l15);
  store_relu_bf16<8, 136>(acc, mb1, buf1, w, quad, l15);
  __syncthreads();
  // L2: 128 -> 128  (act1 in buf1 -> act2 in buf0; X dead)
  do_layer<4, 8, 136, 128>(buf1, wts + 20480, acc, w, quad, l15);
  store_relu_bf16<8, 136>(acc, mb2, buf0, w, quad, l15);
  __syncthreads();
  // L3: 128 -> 64 (no relu), fp32 -> lnbuf in buf1 (act1 dead)
  do_layer<4, 4, 136, 128>(buf0, wts + 36864, acc, w, quad, l15);
  store_preln(acc, mb3, lnbuf, w, quad, l15);
  __syncthreads();

  // ---- LayerNorm stats: one thread per row
  if (tid < 64) {
    float s = 0.f, sq = 0.f;
    #pragma unroll
    for (int c = 0; c < 64; c++) { float x = lnbuf[tid * 65 + c]; s += x; sq += x * x; }
    float mu = s * (1.f / 64.f);
    float var = sq * (1.f / 64.f) - mu * mu;
    stats[2 * tid] = mu;
    stats[2 * tid + 1] = rsqrtf(var + 1e-5f);
  }
  __syncthreads();

  // ---- write msg (float4, coalesced)
  for (int idx = tid; idx < 64 * 16; idx += 256) {
    int r = idx >> 4, c4 = (idx & 15) * 4;
    int e = e0 + r;
    if (e < E) {
      float mu = stats[2 * r], rstd = stats[2 * r + 1];
      float4 o;
      o.x = (lnbuf[r * 65 + c4 + 0] - mu) * rstd * mg[c4 + 0] + mbt[c4 + 0];
      o.y = (lnbuf[r * 65 + c4 + 1] - mu) * rstd * mg[c4 + 1] + mbt[c4 + 1];
      o.z = (lnbuf[r * 65 + c4 + 2] - mu) * rstd * mg[c4 + 2] + mbt[c4 + 2];
      o.w = (lnbuf[r * 65 + c4 + 3] - mu) * rstd * mg[c4 + 3] + mbt[c4 + 3];
      *(float4*)&msg_out[(size_t)e * 64 + c4] = o;
    }
  }
}

// ---------------- aggregation by gather: one node per wave ----------------
__global__ __launch_bounds__(256) void agg_kernel(
    const float* __restrict__ msg, const int* __restrict__ rowptr,
    const int* __restrict__ csr, float* __restrict__ agg, int Nn) {
  int node = (blockIdx.x * 256 + threadIdx.x) >> 6;
  int lane = threadIdx.x & 63;
  if (node >= Nn) return;
  int s = rowptr[node], e = rowptr[node + 1];
  float acc = 0.f;
  int j = s;
  for (; j + 1 < e; j += 2) {       // unroll-2: overlap eid load with row load
    int e0 = csr[j], e1 = csr[j + 1];
    float v0 = msg[(size_t)e0 * 64 + lane];
    float v1 = msg[(size_t)e1 * 64 + lane];
    acc += v0 + v1;
  }
  if (j < e) acc += msg[(size_t)csr[j] * 64 + lane];
  agg[(size_t)node * 64 + lane] = acc;
}

// ---------------- update MLP kernel: 64 nodes / block, 256 threads ----------------
__global__ __launch_bounds__(256, 4) void upd_kernel(
    const float* __restrict__ h, const float* __restrict__ agg,
    const unsigned short* __restrict__ wts,
    const float* __restrict__ ub1, const float* __restrict__ ub2, const float* __restrict__ ub3,
    const float* __restrict__ ug, const float* __restrict__ ubt,
    float* __restrict__ h_new, int Nn) {
  // buf0 17408B: X(64x136) -> act2(64x136) ; buf1 17408B: act1 -> lnbuf
  __shared__ __align__(16) unsigned char smem[17408 + 17408 + 512];
  unsigned short* buf0 = (unsigned short*)smem;
  unsigned short* buf1 = (unsigned short*)(smem + 17408);
  float* stats = (float*)(smem + 17408 + 17408);
  float* lnbuf = (float*)buf1;

  const int tid = threadIdx.x;
  const int w = tid >> 6, lane = tid & 63, quad = lane >> 4, l15 = lane & 15;
  const int n0 = blockIdx.x * 64;

  // ---- stage X = [h | agg] -> buf0 bf16, stride 136
  for (int idx = tid; idx < 64 * 32; idx += 256) {
    int r = idx >> 5, seg = idx & 31;
    int n = n0 + r;
    u16x4 o = {0, 0, 0, 0};
    if (n < Nn) {
      const float* p = (seg < 16) ? h + (size_t)n * 64 + seg * 4
                                  : agg + (size_t)n * 64 + (seg - 16) * 4;
      float4 v = *(const float4*)p;
      o[0] = f2bf(v.x); o[1] = f2bf(v.y); o[2] = f2bf(v.z); o[3] = f2bf(v.w);
    }
    *(u16x4*)&buf0[r * 136 + seg * 4] = o;
  }
  __syncthreads();

  f32x4 acc[8];
  do_layer<4, 8, 136, 128>(buf0, wts + 45056, acc, w, quad, l15);
  store_relu_bf16<8, 136>(acc, ub1, buf1, w, quad, l15);
  __syncthreads();
  do_layer<4, 8, 136, 128>(buf1, wts + 61440, acc, w, quad, l15);
  store_relu_bf16<8, 136>(acc, ub2, buf0, w, quad, l15);
  __syncthreads();
  do_layer<4, 4, 136, 128>(buf0, wts + 77824, acc, w, quad, l15);
  store_preln(acc, ub3, lnbuf, w, quad, l15);
  __syncthreads();

  if (tid < 64) {
    float s = 0.f, sq = 0.f;
    #pragma unroll
    for (int c = 0; c < 64; c++) { float x = lnbuf[tid * 65 + c]; s += x; sq += x * x; }
    float mu = s * (1.f / 64.f);
    float var = sq * (1.f / 64.f) - mu * mu;
    stats[2 * tid] = mu;
    stats[2 * tid + 1] = rsqrtf(var + 1e-5f);
  }
  __syncthreads();

  for (int idx = tid; idx < 64 * 16; idx += 256) {
    int r = idx >> 4, c4 = (idx & 15) * 4;
    int n = n0 + r;
    if (n < Nn) {
      float mu = stats[2 * r], rstd = stats[2 * r + 1];
      const float* hp = h + (size_t)n * 64 + c4;
      float4 o;
      o.x = (lnbuf[r * 65 + c4 + 0] - mu) * rstd * ug[c4 + 0] + ubt[c4 + 0] + hp[0];
      o.y = (lnbuf[r * 65 + c4 + 1] - mu) * rstd * ug[c4 + 1] + ubt[c4 + 1] + hp[1];
      o.z = (lnbuf[r * 65 + c4 + 2] - mu) * rstd * ug[c4 + 2] + ubt[c4 + 2] + hp[2];
      o.w = (lnbuf[r * 65 + c4 + 3] - mu) * rstd * ug[c4 + 3] + ubt[c4 + 3] + hp[3];
      *(float4*)&h_new[(size_t)n * 64 + c4] = o;
    }
  }
}

extern "C" void kernel_launch(void* const* d_in, const int* in_sizes, int n_in,
                              void* d_out, int out_size, void* d_ws, size_t ws_size,
                              hipStream_t stream) {
  const float* h   = (const float*)d_in[0];
  const int*   ei  = (const int*)d_in[1];
  const float* ea  = (const float*)d_in[2];
  const float* mW1 = (const float*)d_in[3];
  const float* mb1 = (const float*)d_in[4];
  const float* mW2 = (const float*)d_in[5];
  const float* mb2 = (const float*)d_in[6];
  const float* mW3 = (const float*)d_in[7];
  const float* mb3 = (const float*)d_in[8];
  const float* mg  = (const float*)d_in[9];
  const float* mbt = (const float*)d_in[10];
  const float* uW1 = (const float*)d_in[11];
  const float* ub1 = (const float*)d_in[12];
  const float* uW2 = (const float*)d_in[13];
  const float* ub2 = (const float*)d_in[14];
  const float* uW3 = (const float*)d_in[15];
  const float* ub3 = (const float*)d_in[16];
  const float* ug  = (const float*)d_in[17];
  const float* ubt = (const float*)d_in[18];

  const int N = in_sizes[0] / 64;
  const int E = in_sizes[2] / 32;
  const int* dstI = ei + E;

  // workspace layout
  char* ws = (char*)d_ws;
  float* agg            = (float*)ws;                         ws += (size_t)N * 64 * 4;   // 12.8 MB
  unsigned short* wts   = (unsigned short*)ws;                ws += 86016 * 2;            // 172 KB
  int* deg              = (int*)ws;                           ws += (size_t)N * 4;
  int* rowptr           = (int*)ws;                           ws += (size_t)(N + 1) * 4;
  ws = (char*)(((size_t)ws + 255) & ~(size_t)255);
  int* cursor           = (int*)ws;                           ws += (size_t)N * 4;
  ws = (char*)(((size_t)ws + 255) & ~(size_t)255);
  int* csr              = (int*)ws;                           ws += (size_t)E * 4;

  float* h_new = (float*)d_out;
  float* msg   = (float*)d_out + (size_t)N * 64;

  hipMemsetAsync(deg, 0, (size_t)N * sizeof(int), stream);
  wconv<<<dim3((86016 + 255) / 256), dim3(256), 0, stream>>>(mW1, mW2, mW3, uW1, uW2, uW3, wts);
  hist_kernel<<<dim3((E + 255) / 256), dim3(256), 0, stream>>>(dstI, deg, E);
  scan_kernel<<<dim3(1), dim3(1024), 0, stream>>>(deg, rowptr, cursor, N);
  scatter_kernel<<<dim3((E + 255) / 256), dim3(256), 0, stream>>>(dstI, cursor, csr, E);
  msg_kernel<<<dim3((E + 63) / 64), dim3(256), 0, stream>>>(
      h, ei, ea, wts, mb1, mb2, mb3, mg, mbt, msg, E);
  agg_kernel<<<dim3((N + 3) / 4), dim3(256), 0, stream>>>(msg, rowptr, csr, agg, N);
  upd_kernel<<<dim3((N + 63) / 64), dim3(256), 0, stream>>>(
      h, agg, wts, ub1, ub2, ub3, ug, ubt, h_new, N);
}

// Round 4
// 488.450 us; speedup vs baseline: 1.4228x; 1.4228x over previous
//
#include <hip/hip_runtime.h>
#include <hip/hip_bf16.h>

// EdgeConv fused GNN. R4: persistent 1024-thread blocks (1/CU, 16 waves = 4/SIMD).
// - All weights in LDS (staged once, XOR-swizzled for conflict-free b128 reads)
// - No barriers in hot loop: each wave owns independent 16-edge tiles
// - MFMA A-frags gathered straight from global into registers (no X staging)
// - Inter-layer transpose via 4KB per-wave LDS act buffer (swizzled)
// - LayerNorm fully in registers via __shfl_xor (no stats phase)
// Aggregation by CSR gather (no fp atomics).

typedef __attribute__((ext_vector_type(8))) short s16x8;   // MFMA A/B frag (8 bf16)
typedef __attribute__((ext_vector_type(4))) float f32x4;   // MFMA C/D frag

__device__ __forceinline__ unsigned short f2bf(float x) {
  union { float f; unsigned u; } v; v.f = x;
  unsigned r = v.u + 0x7fffu + ((v.u >> 16) & 1u);   // RNE
  return (unsigned short)(r >> 16);
}

// load 8 consecutive floats, convert to bf16 frag (packed cvt)
__device__ __forceinline__ s16x8 ld_cvt8(const float* p) {
  float4 a = *(const float4*)p;
  float4 b = *(const float4*)(p + 4);
  union { s16x8 v; __hip_bfloat162 h2[4]; } u;
  float2 t;
  t.x = a.x; t.y = a.y; u.h2[0] = __float22bfloat162_rn(t);
  t.x = a.z; t.y = a.w; u.h2[1] = __float22bfloat162_rn(t);
  t.x = b.x; t.y = b.y; u.h2[2] = __float22bfloat162_rn(t);
  t.x = b.z; t.y = b.w; u.h2[3] = __float22bfloat162_rn(t);
  return u.v;
}

// ---------------- weight transpose+convert into final (swizzled) layout ----------------
// ushort offsets in wts:
//  mW1t @0     : 128 rows x stride 168 (k<160, unswizzled; pad never read)
//  mW2t @21504 : 128 x 128, XOR-swizzled
//  mW3t @37888 :  64 x 128, XOR-swizzled
//  uW1t @46080 : 128 x 128, uW2t @62464, uW3t @78848 (64x128); total 87040 ushorts
__global__ __launch_bounds__(256) void wconv(
    const float* __restrict__ mW1, const float* __restrict__ mW2, const float* __restrict__ mW3,
    const float* __restrict__ uW1, const float* __restrict__ uW2, const float* __restrict__ uW3,
    unsigned short* __restrict__ wts) {
  int t = blockIdx.x * 256 + threadIdx.x;
  const float* src; int K, N, off, base;
  if      (t < 20480) { src = mW1; K = 160; N = 128; off = 0;     base = 0;     }
  else if (t < 36864) { src = mW2; K = 128; N = 128; off = 20480; base = 21504; }
  else if (t < 45056) { src = mW3; K = 128; N = 64;  off = 36864; base = 37888; }
  else if (t < 61440) { src = uW1; K = 128; N = 128; off = 45056; base = 46080; }
  else if (t < 77824) { src = uW2; K = 128; N = 128; off = 61440; base = 62464; }
  else if (t < 86016) { src = uW3; K = 128; N = 64;  off = 77824; base = 78848; }
  else return;
  int local = t - off;
  int n = local / K, k = local - n * K;
  int idx;
  if (K == 160) idx = n * 168 + k;                                        // mW1t: padded, plain
  else          idx = base + n * 128 + ((((k >> 3) ^ (n & 7)) << 3) | (k & 7));
  if (K == 160) idx += 0; else idx += 0;
  wts[(K == 160 ? 0 : 0) + idx] = f2bf(src[k * N + n]);
}

// ---------------- CSR build ----------------
__global__ __launch_bounds__(256) void hist_kernel(const int* __restrict__ dstI,
                                                   int* __restrict__ deg, int E) {
  int t = blockIdx.x * 256 + threadIdx.x;
  if (t < E) atomicAdd(&deg[dstI[t]], 1);
}

__global__ __launch_bounds__(1024) void scan_kernel(const int* __restrict__ deg,
                                                    int* __restrict__ rowptr,
                                                    int* __restrict__ cursor, int Nn) {
  __shared__ int part[1024], offs[1024];
  int t = threadIdx.x;
  int C = (Nn + 1023) / 1024;
  int lo = t * C, hi = lo + C < Nn ? lo + C : Nn;
  int sum = 0;
  for (int i = lo; i < hi; i++) sum += deg[i];
  part[t] = sum;
  __syncthreads();
  if (t == 0) {
    int run = 0;
    for (int i = 0; i < 1024; i++) { offs[i] = run; run += part[i]; }
  }
  __syncthreads();
  int run = offs[t];
  for (int i = lo; i < hi; i++) { rowptr[i] = run; cursor[i] = run; run += deg[i]; }
  if (t == 1023) rowptr[Nn] = offs[1023] + part[1023];
}

__global__ __launch_bounds__(256) void scatter_kernel(const int* __restrict__ dstI,
                                                      int* __restrict__ cursor,
                                                      int* __restrict__ csr, int E) {
  int t = blockIdx.x * 256 + threadIdx.x;
  if (t < E) {
    int pos = atomicAdd(&cursor[dstI[t]], 1);
    csr[pos] = t;
  }
}

// ---------------- message MLP: persistent blocks, 16 waves, 16 edges/tile/wave ----------------
__global__ __launch_bounds__(1024, 4) void msg_kernel(
    const float* __restrict__ h, const int* __restrict__ ei, const float* __restrict__ ea,
    const unsigned short* __restrict__ wts,
    const float* __restrict__ mb1, const float* __restrict__ mb2, const float* __restrict__ mb3,
    const float* __restrict__ mg, const float* __restrict__ mbt,
    float* __restrict__ msg_out, int E) {
  __shared__ __align__(16) unsigned short lds[78848];   // 157,696 B
  const int tid = threadIdx.x;
  // stage all msg weights (46080 ushorts) once
  for (int i = tid; i < 5760; i += 1024)
    *(s16x8*)&lds[i * 8] = *(const s16x8*)&wts[i * 8];
  __syncthreads();

  const int w = tid >> 6, lane = tid & 63, quad = lane >> 4, l15 = lane & 15;
  const int sw = l15 & 7;
  unsigned short* act = &lds[46080 + w * 2048];         // per-wave 4KB, swizzled, stride 128
  const unsigned short* W1 = &lds[0];
  const unsigned short* W2 = &lds[21504];
  const unsigned short* W3 = &lds[37888];
  const int* srcI = ei;
  const int* dstI = ei + E;

  // hoisted per-lane constants
  float b1c[8], b2c[8], b3c[4], gc[4], btc[4];
  #pragma unroll
  for (int nt = 0; nt < 8; nt++) { b1c[nt] = mb1[nt * 16 + l15]; b2c[nt] = mb2[nt * 16 + l15]; }
  #pragma unroll
  for (int nt = 0; nt < 4; nt++) { b3c[nt] = mb3[nt * 16 + l15]; gc[nt] = mg[nt * 16 + l15]; btc[nt] = mbt[nt * 16 + l15]; }

  const int ntiles = (E + 15) >> 4;
  for (int tile = blockIdx.x * 16 + w; tile < ntiles; tile += gridDim.x * 16) {
    const int e0 = tile << 4;
    const int e = e0 + l15;
    const bool ev = e < E;
    int s = 0, d = 0;
    if (ev) { s = srcI[e]; d = dstI[e]; }
    const float* rs = h + (size_t)s * 64 + quad * 8;
    const float* rd = h + (size_t)d * 64 + quad * 8;
    const float* re = ea + (size_t)(ev ? e : 0) * 32 + quad * 8;
    s16x8 fa[5];
    fa[0] = ld_cvt8(rs);      fa[1] = ld_cvt8(rs + 32);
    fa[2] = ld_cvt8(rd);      fa[3] = ld_cvt8(rd + 32);
    fa[4] = ld_cvt8(re);

    // ---- L1: 160 -> 128, B from LDS (stride 168, naturally conflict-free)
    f32x4 acc[8];
    #pragma unroll
    for (int nt = 0; nt < 8; nt++) acc[nt] = (f32x4){0.f, 0.f, 0.f, 0.f};
    #pragma unroll
    for (int kb = 0; kb < 5; kb++) {
      #pragma unroll
      for (int nt = 0; nt < 8; nt++) {
        s16x8 b = *(const s16x8*)&W1[(nt * 16 + l15) * 168 + kb * 32 + quad * 8];
        acc[nt] = __builtin_amdgcn_mfma_f32_16x16x32_bf16(fa[kb], b, acc[nt], 0, 0, 0);
      }
    }
    // act1 = relu(acc + b1), bf16, swizzled (col = nt*16+l15 -> block 2nt+(l15>>3))
    #pragma unroll
    for (int nt = 0; nt < 8; nt++) {
      int cb = 2 * nt + (l15 >> 3);
      #pragma unroll
      for (int r = 0; r < 4; r++) {
        int row = quad * 4 + r;
        float v = acc[nt][r] + b1c[nt];
        v = v > 0.f ? v : 0.f;
        act[row * 128 + ((cb ^ (row & 7)) << 3) + sw] = f2bf(v);
      }
    }

    // ---- L2: 128 -> 128 (A from act, B from W2; both swizzled stride 128)
    f32x4 acc2[8];
    #pragma unroll
    for (int nt = 0; nt < 8; nt++) acc2[nt] = (f32x4){0.f, 0.f, 0.f, 0.f};
    #pragma unroll
    for (int kb = 0; kb < 4; kb++) {
      int blk8 = (((kb << 2) + quad) ^ sw) << 3;
      s16x8 a = *(const s16x8*)&act[l15 * 128 + blk8];
      #pragma unroll
      for (int nt = 0; nt < 8; nt++) {
        s16x8 b = *(const s16x8*)&W2[(nt * 16 + l15) * 128 + blk8];
        acc2[nt] = __builtin_amdgcn_mfma_f32_16x16x32_bf16(a, b, acc2[nt], 0, 0, 0);
      }
    }
    // act2 overwrites act (all reads consumed)
    #pragma unroll
    for (int nt = 0; nt < 8; nt++) {
      int cb = 2 * nt + (l15 >> 3);
      #pragma unroll
      for (int r = 0; r < 4; r++) {
        int row = quad * 4 + r;
        float v = acc2[nt][r] + b2c[nt];
        v = v > 0.f ? v : 0.f;
        act[row * 128 + ((cb ^ (row & 7)) << 3) + sw] = f2bf(v);
      }
    }

    // ---- L3: 128 -> 64
    f32x4 acc3[4];
    #pragma unroll
    for (int nt = 0; nt < 4; nt++) acc3[nt] = (f32x4){0.f, 0.f, 0.f, 0.f};
    #pragma unroll
    for (int kb = 0; kb < 4; kb++) {
      int blk8 = (((kb << 2) + quad) ^ sw) << 3;
      s16x8 a = *(const s16x8*)&act[l15 * 128 + blk8];
      #pragma unroll
      for (int nt = 0; nt < 4; nt++) {
        s16x8 b = *(const s16x8*)&W3[(nt * 16 + l15) * 128 + blk8];
        acc3[nt] = __builtin_amdgcn_mfma_f32_16x16x32_bf16(a, b, acc3[nt], 0, 0, 0);
      }
    }

    // ---- LayerNorm in registers (rows = quad*4+r, cols nt*16+l15) + store
    #pragma unroll
    for (int r = 0; r < 4; r++) {
      float v0 = acc3[0][r] + b3c[0];
      float v1 = acc3[1][r] + b3c[1];
      float v2 = acc3[2][r] + b3c[2];
      float v3 = acc3[3][r] + b3c[3];
      float p = v0 + v1 + v2 + v3;
      float q = v0 * v0 + v1 * v1 + v2 * v2 + v3 * v3;
      #pragma unroll
      for (int m = 1; m <= 8; m <<= 1) {
        p += __shfl_xor(p, m);
        q += __shfl_xor(q, m);
      }
      float mu = p * (1.f / 64.f);
      float var = q * (1.f / 64.f) - mu * mu;
      float rstd = rsqrtf(var + 1e-5f);
      int row = e0 + quad * 4 + r;
      if (row < E) {
        float* mp = msg_out + (size_t)row * 64 + l15;
        mp[0]  = (v0 - mu) * rstd * gc[0] + btc[0];
        mp[16] = (v1 - mu) * rstd * gc[1] + btc[1];
        mp[32] = (v2 - mu) * rstd * gc[2] + btc[2];
        mp[48] = (v3 - mu) * rstd * gc[3] + btc[3];
      }
    }
  }
}

// ---------------- aggregation by gather: one node per wave, unroll-4 ----------------
__global__ __launch_bounds__(256) void agg_kernel(
    const float* __restrict__ msg, const int* __restrict__ rowptr,
    const int* __restrict__ csr, float* __restrict__ agg, int Nn) {
  int node = (blockIdx.x * 256 + threadIdx.x) >> 6;
  int lane = threadIdx.x & 63;
  if (node >= Nn) return;
  int s = rowptr[node], e = rowptr[node + 1];
  float a0 = 0.f, a1 = 0.f, a2 = 0.f, a3 = 0.f;
  int j = s;
  for (; j + 3 < e; j += 4) {
    int e0 = csr[j], e1 = csr[j + 1], e2 = csr[j + 2], e3 = csr[j + 3];
    a0 += msg[(size_t)e0 * 64 + lane];
    a1 += msg[(size_t)e1 * 64 + lane];
    a2 += msg[(size_t)e2 * 64 + lane];
    a3 += msg[(size_t)e3 * 64 + lane];
  }
  for (; j < e; j++) a0 += msg[(size_t)csr[j] * 64 + lane];
  agg[(size_t)node * 64 + lane] = a0 + a1 + a2 + a3;
}

// ---------------- update MLP: same structure, 16 nodes/tile/wave ----------------
__global__ __launch_bounds__(1024, 4) void upd_kernel(
    const float* __restrict__ h, const float* __restrict__ agg,
    const unsigned short* __restrict__ wts,
    const float* __restrict__ ub1, const float* __restrict__ ub2, const float* __restrict__ ub3,
    const float* __restrict__ ug, const float* __restrict__ ubt,
    float* __restrict__ h_new, int Nn) {
  __shared__ __align__(16) unsigned short lds[73728];   // 147,456 B
  const int tid = threadIdx.x;
  for (int i = tid; i < 5120; i += 1024)
    *(s16x8*)&lds[i * 8] = *(const s16x8*)&wts[46080 + i * 8];
  __syncthreads();

  const int w = tid >> 6, lane = tid & 63, quad = lane >> 4, l15 = lane & 15;
  const int sw = l15 & 7;
  unsigned short* act = &lds[40960 + w * 2048];
  const unsigned short* W1 = &lds[0];
  const unsigned short* W2 = &lds[16384];
  const unsigned short* W3 = &lds[32768];

  float b1c[8], b2c[8], b3c[4], gc[4], btc[4];
  #pragma unroll
  for (int nt = 0; nt < 8; nt++) { b1c[nt] = ub1[nt * 16 + l15]; b2c[nt] = ub2[nt * 16 + l15]; }
  #pragma unroll
  for (int nt = 0; nt < 4; nt++) { b3c[nt] = ub3[nt * 16 + l15]; gc[nt] = ug[nt * 16 + l15]; btc[nt] = ubt[nt * 16 + l15]; }

  const int ntiles = (Nn + 15) >> 4;
  for (int tile = blockIdx.x * 16 + w; tile < ntiles; tile += gridDim.x * 16) {
    const int n0 = tile << 4;
    const int n = n0 + l15;
    const int nc = n < Nn ? n : 0;
    const float* rh = h + (size_t)nc * 64 + quad * 8;
    const float* rg = agg + (size_t)nc * 64 + quad * 8;
    s16x8 fa[4];
    fa[0] = ld_cvt8(rh);  fa[1] = ld_cvt8(rh + 32);
    fa[2] = ld_cvt8(rg);  fa[3] = ld_cvt8(rg + 32);

    f32x4 acc[8];
    #pragma unroll
    for (int nt = 0; nt < 8; nt++) acc[nt] = (f32x4){0.f, 0.f, 0.f, 0.f};
    #pragma unroll
    for (int kb = 0; kb < 4; kb++) {
      int blk8 = (((kb << 2) + quad) ^ sw) << 3;
      #pragma unroll
      for (int nt = 0; nt < 8; nt++) {
        s16x8 b = *(const s16x8*)&W1[(nt * 16 + l15) * 128 + blk8];
        acc[nt] = __builtin_amdgcn_mfma_f32_16x16x32_bf16(fa[kb], b, acc[nt], 0, 0, 0);
      }
    }
    #pragma unroll
    for (int nt = 0; nt < 8; nt++) {
      int cb = 2 * nt + (l15 >> 3);
      #pragma unroll
      for (int r = 0; r < 4; r++) {
        int row = quad * 4 + r;
        float v = acc[nt][r] + b1c[nt];
        v = v > 0.f ? v : 0.f;
        act[row * 128 + ((cb ^ (row & 7)) << 3) + sw] = f2bf(v);
      }
    }

    f32x4 acc2[8];
    #pragma unroll
    for (int nt = 0; nt < 8; nt++) acc2[nt] = (f32x4){0.f, 0.f, 0.f, 0.f};
    #pragma unroll
    for (int kb = 0; kb < 4; kb++) {
      int blk8 = (((kb << 2) + quad) ^ sw) << 3;
      s16x8 a = *(const s16x8*)&act[l15 * 128 + blk8];
      #pragma unroll
      for (int nt = 0; nt < 8; nt++) {
        s16x8 b = *(const s16x8*)&W2[(nt * 16 + l15) * 128 + blk8];
        acc2[nt] = __builtin_amdgcn_mfma_f32_16x16x32_bf16(a, b, acc2[nt], 0, 0, 0);
      }
    }
    #pragma unroll
    for (int nt = 0; nt < 8; nt++) {
      int cb = 2 * nt + (l15 >> 3);
      #pragma unroll
      for (int r = 0; r < 4; r++) {
        int row = quad * 4 + r;
        float v = acc2[nt][r] + b2c[nt];
        v = v > 0.f ? v : 0.f;
        act[row * 128 + ((cb ^ (row & 7)) << 3) + sw] = f2bf(v);
      }
    }

    f32x4 acc3[4];
    #pragma unroll
    for (int nt = 0; nt < 4; nt++) acc3[nt] = (f32x4){0.f, 0.f, 0.f, 0.f};
    #pragma unroll
    for (int kb = 0; kb < 4; kb++) {
      int blk8 = (((kb << 2) + quad) ^ sw) << 3;
      s16x8 a = *(const s16x8*)&act[l15 * 128 + blk8];
      #pragma unroll
      for (int nt = 0; nt < 4; nt++) {
        s16x8 b = *(const s16x8*)&W3[(nt * 16 + l15) * 128 + blk8];
        acc3[nt] = __builtin_amdgcn_mfma_f32_16x16x32_bf16(a, b, acc3[nt], 0, 0, 0);
      }
    }

    #pragma unroll
    for (int r = 0; r < 4; r++) {
      float v0 = acc3[0][r] + b3c[0];
      float v1 = acc3[1][r] + b3c[1];
      float v2 = acc3[2][r] + b3c[2];
      float v3 = acc3[3][r] + b3c[3];
      float p = v0 + v1 + v2 + v3;
      float q = v0 * v0 + v1 * v1 + v2 * v2 + v3 * v3;
      #pragma unroll
      for (int m = 1; m <= 8; m <<= 1) {
        p += __shfl_xor(p, m);
        q += __shfl_xor(q, m);
      }
      float mu = p * (1.f / 64.f);
      float var = q * (1.f / 64.f) - mu * mu;
      float rstd = rsqrtf(var + 1e-5f);
      int row = n0 + quad * 4 + r;
      if (row < Nn) {
        const float* hp = h + (size_t)row * 64 + l15;
        float* op = h_new + (size_t)row * 64 + l15;
        op[0]  = (v0 - mu) * rstd * gc[0] + btc[0] + hp[0];
        op[16] = (v1 - mu) * rstd * gc[1] + btc[1] + hp[16];
        op[32] = (v2 - mu) * rstd * gc[2] + btc[2] + hp[32];
        op[48] = (v3 - mu) * rstd * gc[3] + btc[3] + hp[48];
      }
    }
  }
}

extern "C" void kernel_launch(void* const* d_in, const int* in_sizes, int n_in,
                              void* d_out, int out_size, void* d_ws, size_t ws_size,
                              hipStream_t stream) {
  const float* h   = (const float*)d_in[0];
  const int*   ei  = (const int*)d_in[1];
  const float* ea  = (const float*)d_in[2];
  const float* mW1 = (const float*)d_in[3];
  const float* mb1 = (const float*)d_in[4];
  const float* mW2 = (const float*)d_in[5];
  const float* mb2 = (const float*)d_in[6];
  const float* mW3 = (const float*)d_in[7];
  const float* mb3 = (const float*)d_in[8];
  const float* mg  = (const float*)d_in[9];
  const float* mbt = (const float*)d_in[10];
  const float* uW1 = (const float*)d_in[11];
  const float* ub1 = (const float*)d_in[12];
  const float* uW2 = (const float*)d_in[13];
  const float* ub2 = (const float*)d_in[14];
  const float* uW3 = (const float*)d_in[15];
  const float* ub3 = (const float*)d_in[16];
  const float* ug  = (const float*)d_in[17];
  const float* ubt = (const float*)d_in[18];

  const int N = in_sizes[0] / 64;
  const int E = in_sizes[2] / 32;
  const int* dstI = ei + E;

  char* ws = (char*)d_ws;
  float* agg          = (float*)ws;              ws += (size_t)N * 64 * 4;
  unsigned short* wts = (unsigned short*)ws;     ws += 87040 * 2;
  ws = (char*)(((size_t)ws + 255) & ~(size_t)255);
  int* deg            = (int*)ws;                ws += (size_t)N * 4;
  int* rowptr         = (int*)ws;                ws += (size_t)(N + 1) * 4;
  ws = (char*)(((size_t)ws + 255) & ~(size_t)255);
  int* cursor         = (int*)ws;                ws += (size_t)N * 4;
  ws = (char*)(((size_t)ws + 255) & ~(size_t)255);
  int* csr            = (int*)ws;                ws += (size_t)E * 4;

  float* h_new = (float*)d_out;
  float* msg   = (float*)d_out + (size_t)N * 64;

  hipMemsetAsync(deg, 0, (size_t)N * sizeof(int), stream);
  wconv<<<dim3((86016 + 255) / 256), dim3(256), 0, stream>>>(mW1, mW2, mW3, uW1, uW2, uW3, wts);
  hist_kernel<<<dim3((E + 255) / 256), dim3(256), 0, stream>>>(dstI, deg, E);
  scan_kernel<<<dim3(1), dim3(1024), 0, stream>>>(deg, rowptr, cursor, N);
  scatter_kernel<<<dim3((E + 255) / 256), dim3(256), 0, stream>>>(dstI, cursor, csr, E);
  msg_kernel<<<dim3(256), dim3(1024), 0, stream>>>(
      h, ei, ea, wts, mb1, mb2, mb3, mg, mbt, msg, E);
  agg_kernel<<<dim3((N + 3) / 4), dim3(256), 0, stream>>>(msg, rowptr, csr, agg, N);
  upd_kernel<<<dim3(256), dim3(1024), 0, stream>>>(
      h, agg, wts, ub1, ub2, ub3, ug, ubt, h_new, N);
}